// Round 4
// baseline (193.629 us; speedup 1.0000x reference)
//
#include <hip/hip_runtime.h>
#include <hip/hip_bf16.h>
#include <math.h>

#define N 4096
#define K 2048
#define NC 32
#define CAP 256          // max rows per class list
#define MARGIN 0.3f

#define BK 32            // K elements per pipeline stage
#define NITER (K / BK)   // 64
#define STAGE_BYTES 16384 // A 8KB + B 8KB per stage
#define DIAG_BLOCKS 96   // 32 classes x {(0,0),(0,1),(1,1)} 128-subtiles
#define CROSS_BLOCKS 64  // 2 i-tiles x 32 j-tiles of 128
#define GRID (DIAG_BLOCKS + CROSS_BLOCKS)

typedef float f32x4 __attribute__((ext_vector_type(4)));
typedef __bf16 bf16x8 __attribute__((ext_vector_type(8)));

__device__ __forceinline__ void glds16(const void* g, void* l) {
  __builtin_amdgcn_global_load_lds(
      (const __attribute__((address_space(1))) void*)g,
      (__attribute__((address_space(3))) void*)l, 16, 0, 0);
}

__device__ __forceinline__ int imin(int a, int b) { return a < b ? a : b; }

// ---------------------------------------------------------------------------
// Kernel 1: fp32 -> bf16 convert (in-place row order) + sum-of-squares +
// ap/an init + class/nonzero index-list build. One block per row.
// Counters (cls_cnt[32], nzc, done) pre-zeroed via hipMemsetAsync.
// ---------------------------------------------------------------------------
__global__ __launch_bounds__(256) void convert_kernel(
    const float* __restrict__ X, const int* __restrict__ tg,
    __bf16* __restrict__ Xb, float* __restrict__ sq,
    unsigned int* __restrict__ ap, unsigned int* __restrict__ an,
    int* __restrict__ cls_cnt, int* __restrict__ clslist,
    int* __restrict__ nzc, int* __restrict__ nzlist) {
  int row = blockIdx.x;
  int t = threadIdx.x;
  const float* xr = X + (size_t)row * K;

  float4 v0 = ((const float4*)xr)[t * 2 + 0];
  float4 v1 = ((const float4*)xr)[t * 2 + 1];

  float s = v0.x * v0.x + v0.y * v0.y + v0.z * v0.z + v0.w * v0.w +
            v1.x * v1.x + v1.y * v1.y + v1.z * v1.z + v1.w * v1.w;

  bf16x8 b;
  b[0] = (__bf16)v0.x; b[1] = (__bf16)v0.y; b[2] = (__bf16)v0.z; b[3] = (__bf16)v0.w;
  b[4] = (__bf16)v1.x; b[5] = (__bf16)v1.y; b[6] = (__bf16)v1.z; b[7] = (__bf16)v1.w;
  ((bf16x8*)(Xb + (size_t)row * K))[t] = b;

  #pragma unroll
  for (int m = 32; m; m >>= 1) s += __shfl_xor(s, m);
  __shared__ float wred[4];
  if ((t & 63) == 0) wred[t >> 6] = s;
  __syncthreads();
  if (t == 0) {
    sq[row] = wred[0] + wred[1] + wred[2] + wred[3];
    ap[row] = 0u;           // identity for max of non-negative floats
    an[row] = 0x7f800000u;  // +inf
    int c = tg[row];
    int k = atomicAdd(&cls_cnt[c], 1);
    if (k < CAP) clslist[c * CAP + k] = row;
    if (c != 0) {
      int k2 = atomicAdd(nzc, 1);
      nzlist[k2] = row;
    }
  }
}

// ---------------------------------------------------------------------------
// Kernel 2: 128x128 MFMA tiles gathered through index lists, BK=32, 4-stage
// async global_load_lds pipeline (one s_barrier/iter, vmcnt(8) steady state).
// XOR bank swizzle: global chunk (slot ^ ((row>>1)&3)) stored at slot.
// Diag (same class) -> ap max (both sides for the (0,1) subtile);
// cross (class0 x nonzero) -> an min (both sides). Reduce on d^2, sqrt late.
// Last block (ticket) computes the final loss.
// ---------------------------------------------------------------------------
__global__ __launch_bounds__(256) void gemm_reduce_kernel(
    const __bf16* __restrict__ Xb, const float* __restrict__ sq,
    const int* __restrict__ cls_cnt, const int* __restrict__ clslist,
    const int* __restrict__ nzc, const int* __restrict__ nzlist,
    const int* __restrict__ tg, unsigned int* __restrict__ ap,
    unsigned int* __restrict__ an, int* __restrict__ done,
    float* __restrict__ out) {
  __shared__ __align__(16) char sAB[4][STAGE_BYTES];  // 64 KiB
  __shared__ int s_islast;
  __shared__ float wred[4];

  int b = blockIdx.x;
  int t = threadIdx.x;

  bool active = true, diag = true, colside = false;
  const int* listI = clslist; const int* listJ = clslist;
  int baseI = 0, baseJ = 0, nI = 1, nJ = 1;
  if (b < DIAG_BLOCKS) {
    int c = b / 3, sub = b % 3;
    int sti = (sub == 2) ? 1 : 0, stj = (sub == 0) ? 0 : 1;
    int n = cls_cnt[c];
    if (!(n > 0 && sti * 128 < n && stj * 128 < n)) active = false;
    listI = listJ = clslist + c * CAP;
    nI = nJ = n > 0 ? n : 1;
    baseI = sti * 128; baseJ = stj * 128;
    colside = (sub == 1);
  } else {
    int idx = b - DIAG_BLOCKS;
    int it = idx >> 5, jt = idx & 31;
    int n0 = cls_cnt[0], nz = *nzc;
    if (!(n0 > 0 && nz > 0 && it * 128 < n0 && jt * 128 < nz)) active = false;
    listI = clslist; nI = n0 > 0 ? n0 : 1; baseI = it * 128;
    listJ = nzlist;  nJ = nz > 0 ? nz : 1; baseJ = jt * 128;
    diag = false; colside = true;
  }

  if (active) {
    int w = t >> 6, l = t & 63;
    int wi = w >> 1, wj = w & 1;
    int quad = l >> 4, lr = l & 15;

    // Staging: thread t covers LDS offsets t*16 + r*4096 per matrix.
    // row = r*64 + (t>>2), slot = t&3, global chunk = slot ^ ((row>>1)&3).
    const char* gA[2]; const char* gB[2];
    int cbg = (t & 3) ^ ((t >> 3) & 3);
    #pragma unroll
    for (int r = 0; r < 2; r++) {
      int row_l = r * 64 + (t >> 2);
      int ia = imin(baseI + row_l, nI - 1);
      int ja = imin(baseJ + row_l, nJ - 1);
      gA[r] = (const char*)Xb + (size_t)listI[ia] * (K * 2) + cbg * 16;
      gB[r] = (const char*)Xb + (size_t)listJ[ja] * (K * 2) + cbg * 16;
    }

    // Fragment offsets: row*64 + (quad ^ ((lr>>1)&3))*16; B region at +8192.
    int aoff[4], boff[4];
    int sw = (quad ^ ((lr >> 1) & 3)) * 16;
    #pragma unroll
    for (int ti = 0; ti < 4; ti++) {
      aoff[ti] = (wi * 64 + ti * 16 + lr) * 64 + sw;
      boff[ti] = (wj * 64 + ti * 16 + lr) * 64 + sw + 8192;
    }

    f32x4 acc[4][4];
    #pragma unroll
    for (int a = 0; a < 4; a++)
      #pragma unroll
      for (int c2 = 0; c2 < 4; c2++) acc[a][c2] = (f32x4)0.f;

    auto stage = [&](int sbuf, int itk) {
      char* dst = sAB[sbuf] + t * 16;
      int koff = itk * 64;
      glds16(gA[0] + koff, dst);
      glds16(gA[1] + koff, dst + 4096);
      glds16(gB[0] + koff, dst + 8192);
      glds16(gB[1] + koff, dst + 12288);
    };

    auto compute = [&](int sbuf) {
      const char* base = sAB[sbuf];
      bf16x8 af[4], bfv[4];
      #pragma unroll
      for (int ti = 0; ti < 4; ti++) {
        af[ti] = *(const bf16x8*)(base + aoff[ti]);
        bfv[ti] = *(const bf16x8*)(base + boff[ti]);
      }
      #pragma unroll
      for (int ti = 0; ti < 4; ti++)
        #pragma unroll
        for (int tj = 0; tj < 4; tj++)
          acc[ti][tj] = __builtin_amdgcn_mfma_f32_16x16x32_bf16(
              af[ti], bfv[tj], acc[ti][tj], 0, 0, 0);
    };

    stage(0, 0); stage(1, 1); stage(2, 2);
    for (int itk = 0; itk < NITER - 2; ++itk) {
      __builtin_amdgcn_s_waitcnt(0x0F78);  // vmcnt(8): stage itk landed
      __builtin_amdgcn_s_barrier();
      if (itk + 3 < NITER) stage((itk + 3) & 3, itk + 3);
      __builtin_amdgcn_sched_barrier(0);
      compute(itk & 3);
    }
    __builtin_amdgcn_s_waitcnt(0x0F74);  // vmcnt(4)
    __builtin_amdgcn_s_barrier();
    __builtin_amdgcn_sched_barrier(0);
    compute((NITER - 2) & 3);
    __builtin_amdgcn_s_waitcnt(0x0F70);  // vmcnt(0)
    __builtin_amdgcn_s_barrier();
    __builtin_amdgcn_sched_barrier(0);
    compute((NITER - 1) & 3);

    // Epilogue. C/D: col = lane&15 (j), row = quad*4 + reg (i). Reduce d^2.
    int origj[4]; float sqj[4];
    #pragma unroll
    for (int tj = 0; tj < 4; tj++) {
      int jr = imin(baseJ + wj * 64 + tj * 16 + lr, nJ - 1);
      origj[tj] = listJ[jr];
      sqj[tj] = sq[origj[tj]];
    }

    float cred[4];
    #pragma unroll
    for (int tj = 0; tj < 4; tj++) cred[tj] = diag ? 0.f : INFINITY;

    #pragma unroll
    for (int ti = 0; ti < 4; ti++) {
      #pragma unroll
      for (int r = 0; r < 4; r++) {
        int ir = imin(baseI + wi * 64 + ti * 16 + quad * 4 + r, nI - 1);
        int origi = listI[ir];
        float sqi = sq[origi];
        float v = diag ? 0.f : INFINITY;
        #pragma unroll
        for (int tj = 0; tj < 4; tj++) {
          float d2 = fmaxf(sqi + sqj[tj] - 2.f * acc[ti][tj][r], 1e-12f);
          v = diag ? fmaxf(v, d2) : fminf(v, d2);
          cred[tj] = diag ? fmaxf(cred[tj], d2) : fminf(cred[tj], d2);
        }
        #pragma unroll
        for (int m = 1; m < 16; m <<= 1) {
          float o = __shfl_xor(v, m);
          v = diag ? fmaxf(v, o) : fminf(v, o);
        }
        if (lr == 0) {
          unsigned int u = __float_as_uint(sqrtf(v));
          if (diag) atomicMax(ap + origi, u);
          else      atomicMin(an + origi, u);
        }
      }
    }
    if (colside) {
      #pragma unroll
      for (int tj = 0; tj < 4; tj++) {
        float v = cred[tj];
        float o = __shfl_xor(v, 16);
        v = diag ? fmaxf(v, o) : fminf(v, o);
        o = __shfl_xor(v, 32);
        v = diag ? fmaxf(v, o) : fminf(v, o);
        if (quad == 0) {
          unsigned int u = __float_as_uint(sqrtf(v));
          if (diag) atomicMax(ap + origj[tj], u);
          else      atomicMin(an + origj[tj], u);
        }
      }
    }
  }

  // ---- last-block ticket: final loss reduction --------------------------
  __syncthreads();
  if (t == 0) {
    __threadfence();
    int ticket = __hip_atomic_fetch_add(done, 1, __ATOMIC_ACQ_REL,
                                        __HIP_MEMORY_SCOPE_AGENT);
    s_islast = (ticket == GRID - 1);
  }
  __syncthreads();
  if (s_islast) {
    int n0 = cls_cnt[0], nz = *nzc, t0 = tg[0];
    int has = (t0 == 0) ? (nz > 0) : (n0 > 0);
    float s = 0.f;
    for (int i = t; i < N; i += 256) {
      unsigned int au = __hip_atomic_load(ap + i, __ATOMIC_RELAXED,
                                          __HIP_MEMORY_SCOPE_AGENT);
      unsigned int nu = __hip_atomic_load(an + i, __ATOMIC_RELAXED,
                                          __HIP_MEMORY_SCOPE_AGENT);
      float a = __uint_as_float(au);
      float bb = has ? __uint_as_float(nu) : 0.f;
      s += fmaxf(a - bb + MARGIN, 0.f);
    }
    #pragma unroll
    for (int m = 32; m; m >>= 1) s += __shfl_xor(s, m);
    if ((t & 63) == 0) wred[t >> 6] = s;
    __syncthreads();
    if (t == 0) out[0] = (wred[0] + wred[1] + wred[2] + wred[3]) / (float)N;
  }
}

// ---------------------------------------------------------------------------
extern "C" void kernel_launch(void* const* d_in, const int* in_sizes, int n_in,
                              void* d_out, int out_size, void* d_ws,
                              size_t ws_size, hipStream_t stream) {
  const float* X = (const float*)d_in[0];
  const int* tg = (const int*)d_in[1];
  float* out = (float*)d_out;

  char* ws = (char*)d_ws;
  __bf16* Xb = (__bf16*)ws;
  size_t o = (size_t)N * K * 2;
  float* sq = (float*)(ws + o); o += (size_t)N * 4;
  unsigned int* ap = (unsigned int*)(ws + o); o += (size_t)N * 4;
  unsigned int* an = (unsigned int*)(ws + o); o += (size_t)N * 4;
  int* clslist = (int*)(ws + o); o += (size_t)NC * CAP * 4;
  int* nzlist = (int*)(ws + o); o += (size_t)N * 4;
  int* cls_cnt = (int*)(ws + o);  // 32 cnt + nzc + done, contiguous
  int* nzc = cls_cnt + NC;
  int* done = cls_cnt + NC + 1;
  size_t zero_bytes = (NC + 2) * sizeof(int);

  hipMemsetAsync(cls_cnt, 0, zero_bytes, stream);
  convert_kernel<<<N, 256, 0, stream>>>(X, tg, Xb, sq, ap, an, cls_cnt,
                                        clslist, nzc, nzlist);
  gemm_reduce_kernel<<<GRID, 256, 0, stream>>>(Xb, sq, cls_cnt, clslist, nzc,
                                               nzlist, tg, ap, an, done, out);
}

// Round 5
// 145.378 us; speedup vs baseline: 1.3319x; 1.3319x over previous
//
#include <hip/hip_runtime.h>
#include <hip/hip_bf16.h>
#include <math.h>

#define N 4096
#define K 2048
#define NC 32
#define MARGIN 0.3f

#define BK 64
#define NITER (K / BK)   // 32
#define GRID 512
#define MAXTILES 4096

typedef float f32x4 __attribute__((ext_vector_type(4)));
typedef __bf16 bf16x8 __attribute__((ext_vector_type(8)));

__device__ __forceinline__ void glds16(const void* g, void* l) {
  __builtin_amdgcn_global_load_lds(
      (const __attribute__((address_space(1))) void*)g,
      (__attribute__((address_space(3))) void*)l, 16, 0, 0);
}

__device__ __forceinline__ int imin(int a, int b) { return a < b ? a : b; }

// ---------------------------------------------------------------------------
// Kernel 0: planner. Histogram -> offsets/cursors, row0_has_zero flag,
// done=0, and the 64x64 tile work-list:
//   diag (class c): subtiles si<=sj of ceil(n_c/64); si<sj reduce both sides.
//   cross: class0 i-tiles x nonzero j-tiles; always both sides.
// Tile desc int4: x = i0 | (flags<<28) [bit28=diag, bit29=colside],
//                 y = j0, z = iend, w = jend (sorted-row space).
// ---------------------------------------------------------------------------
__global__ __launch_bounds__(256) void plan_kernel(
    const int* __restrict__ tg, int* __restrict__ cursor,
    int* __restrict__ flag, int* __restrict__ done, int* __restrict__ Tp,
    int4* __restrict__ tiles) {
  __shared__ int h[NC], soff[NC], stb[NC + 1];
  int t = threadIdx.x;
  if (t < NC) h[t] = 0;
  __syncthreads();
  const int4* tg4 = (const int4*)tg;
  for (int i = t; i < N / 4; i += 256) {
    int4 v = tg4[i];
    atomicAdd(&h[v.x], 1); atomicAdd(&h[v.y], 1);
    atomicAdd(&h[v.z], 1); atomicAdd(&h[v.w], 1);
  }
  __syncthreads();
  if (t == 0) {
    int acc = 0, tacc = 0;
    for (int c = 0; c < NC; c++) {
      int n = h[c];
      soff[c] = acc;
      cursor[c] = acc;
      acc += n;
      stb[c] = tacc;
      int tt = (n + 63) >> 6;
      tacc += (tt * (tt + 1)) >> 1;
    }
    stb[NC] = tacc;
    int n0 = h[0], nz = N - n0;
    int t0b = (n0 + 63) >> 6, tzb = (nz + 63) >> 6;
    Tp[0] = tacc + ((n0 > 0 && nz > 0) ? t0b * tzb : 0);
    flag[0] = (tg[0] == 0) ? (nz > 0) : (n0 > 0);
    done[0] = 0;
  }
  __syncthreads();
  if (t < NC && h[t] > 0) {
    int n = h[t], o = soff[t];
    int tt = (n + 63) >> 6;
    int idx = stb[t];
    for (int si = 0; si < tt; si++)
      for (int sj = si; sj < tt; sj++) {
        int fl = (si < sj) ? 3 : 1;
        tiles[idx++] = make_int4((o + si * 64) | (fl << 28), o + sj * 64,
                                 o + n, o + n);
      }
  }
  int n0 = h[0], nz = N - n0;
  if (n0 > 0 && nz > 0) {
    int t0b = (n0 + 63) >> 6, tzb = (nz + 63) >> 6;
    int base = stb[NC];
    for (int k2 = t; k2 < t0b * tzb; k2 += 256) {
      int si = k2 / tzb, sj = k2 - si * tzb;
      tiles[base + k2] = make_int4((si * 64) | (2 << 28), n0 + sj * 64, n0, N);
    }
  }
}

// ---------------------------------------------------------------------------
// Kernel 1: fp32 -> bf16 convert + class-sorted scatter + sum-of-squares +
// ap/an init. One block per original row.
// ---------------------------------------------------------------------------
__global__ __launch_bounds__(256) void convert_kernel(
    const float* __restrict__ X, const int* __restrict__ tg,
    __bf16* __restrict__ Xg, float* __restrict__ sqg,
    unsigned int* __restrict__ ap, unsigned int* __restrict__ an,
    int* __restrict__ cursor) {
  int row = blockIdx.x;
  int t = threadIdx.x;
  const float* xr = X + (size_t)row * K;

  float4 v0 = ((const float4*)xr)[t * 2 + 0];
  float4 v1 = ((const float4*)xr)[t * 2 + 1];

  float s = v0.x * v0.x + v0.y * v0.y + v0.z * v0.z + v0.w * v0.w +
            v1.x * v1.x + v1.y * v1.y + v1.z * v1.z + v1.w * v1.w;

  bf16x8 b;
  b[0] = (__bf16)v0.x; b[1] = (__bf16)v0.y; b[2] = (__bf16)v0.z; b[3] = (__bf16)v0.w;
  b[4] = (__bf16)v1.x; b[5] = (__bf16)v1.y; b[6] = (__bf16)v1.z; b[7] = (__bf16)v1.w;

  #pragma unroll
  for (int m = 32; m; m >>= 1) s += __shfl_xor(s, m);

  __shared__ float wred[4];
  __shared__ int spos;
  if ((t & 63) == 0) wred[t >> 6] = s;
  if (t == 0) spos = atomicAdd(&cursor[tg[row]], 1);
  __syncthreads();
  int pos = spos;

  ((bf16x8*)(Xg + (size_t)pos * K))[t] = b;
  if (t == 0) {
    sqg[pos] = wred[0] + wred[1] + wred[2] + wred[3];
    ap[pos] = 0u;           // identity for max of non-negative
    an[pos] = 0x7f800000u;  // +inf
  }
}

// ---------------------------------------------------------------------------
// Kernel 2: persistent blocks over the tile list. 64x64 tile, BK=64,
// 3-stage async global_load_lds pipeline (one s_barrier/iter, vmcnt(4)
// steady state), XOR bank swizzle. Reduce d^2, sqrt late. Ticket -> loss.
// ---------------------------------------------------------------------------
__global__ __launch_bounds__(256, 3) void gemm_reduce_kernel(
    const __bf16* __restrict__ Xg, const float* __restrict__ sq,
    const int* __restrict__ Tp, const int4* __restrict__ tiles,
    const int* __restrict__ flag, int* __restrict__ done,
    unsigned int* __restrict__ ap, unsigned int* __restrict__ an,
    float* __restrict__ out) {
  __shared__ __align__(16) char sAB[3][16384];  // 48 KiB -> 3 blocks/CU
  __shared__ int s_islast;
  __shared__ float wred[4];

  int t = threadIdx.x;
  int w = t >> 6, l = t & 63;
  int wi = w >> 1, wj = w & 1;
  int quad = l >> 4, lr = l & 15;

  // Fragment LDS byte offsets (tile-invariant). Row stride 128B; chunk
  // ch = h*4+quad stored at slot ch ^ (row&7), row&7 == lr&7.
  int aoff[2][2], boff[2][2];
  #pragma unroll
  for (int ti2 = 0; ti2 < 2; ti2++)
    #pragma unroll
    for (int h = 0; h < 2; h++) {
      int sw = (((h << 2) + quad) ^ (lr & 7)) << 4;
      aoff[ti2][h] = (wi * 32 + ti2 * 16 + lr) * 128 + sw;
      boff[ti2][h] = (wj * 32 + ti2 * 16 + lr) * 128 + sw + 8192;
    }

  int rr = t >> 3, slot = t & 7;
  int T = Tp[0];

  for (int tid = blockIdx.x; tid < T; tid += GRID) {
    int4 dsc = tiles[tid];
    unsigned fl = (unsigned)dsc.x >> 28;
    int i0 = dsc.x & 0x0FFFFFFF;
    int j0 = dsc.y, iend = dsc.z, jend = dsc.w;
    bool diag = fl & 1, colside = (fl & 2) != 0;

    // Staging: thread t fills LDS (row_l = r*32 + t>>3, slot = t&7) from
    // global chunk cbg = slot ^ (row_l & 7). 1KB coalesced per wave-instr.
    const char* gA[2]; const char* gB[2];
    #pragma unroll
    for (int r = 0; r < 2; r++) {
      int row_l = r * 32 + rr;
      int cbg = slot ^ (row_l & 7);
      int ia = imin(i0 + row_l, iend - 1);
      int ja = imin(j0 + row_l, jend - 1);
      gA[r] = (const char*)(Xg + (size_t)ia * K) + cbg * 16;
      gB[r] = (const char*)(Xg + (size_t)ja * K) + cbg * 16;
    }

    f32x4 acc[2][2];
    acc[0][0] = (f32x4)0.f; acc[0][1] = (f32x4)0.f;
    acc[1][0] = (f32x4)0.f; acc[1][1] = (f32x4)0.f;

    auto stage = [&](int buf, int it) {
      char* base = sAB[buf] + t * 16;
      int koff = it * 128;  // BK*2 bytes
      glds16(gA[0] + koff, base);
      glds16(gA[1] + koff, base + 4096);
      glds16(gB[0] + koff, base + 8192);
      glds16(gB[1] + koff, base + 12288);
    };

    auto compute = [&](int buf) {
      const char* base = sAB[buf];
      bf16x8 af[2][2], bfr[2][2];
      #pragma unroll
      for (int ti2 = 0; ti2 < 2; ti2++)
        #pragma unroll
        for (int h = 0; h < 2; h++) {
          af[ti2][h] = *(const bf16x8*)(base + aoff[ti2][h]);
          bfr[ti2][h] = *(const bf16x8*)(base + boff[ti2][h]);
        }
      #pragma unroll
      for (int h = 0; h < 2; h++)
        #pragma unroll
        for (int ti2 = 0; ti2 < 2; ti2++)
          #pragma unroll
          for (int tj2 = 0; tj2 < 2; tj2++)
            acc[ti2][tj2] = __builtin_amdgcn_mfma_f32_16x16x32_bf16(
                af[ti2][h], bfr[tj2][h], acc[ti2][tj2], 0, 0, 0);
    };

    stage(0, 0);
    stage(1, 1);
    int pbuf = 2, cbuf = 0;
    for (int it = 0; it < NITER; ++it) {
      if (it < NITER - 1) __builtin_amdgcn_s_waitcnt(0x0F74);  // vmcnt(4)
      else __builtin_amdgcn_s_waitcnt(0x0F70);                 // vmcnt(0)
      __builtin_amdgcn_s_barrier();
      if (it + 2 < NITER) {
        stage(pbuf, it + 2);
        pbuf = (pbuf == 2) ? 0 : pbuf + 1;
      }
      __builtin_amdgcn_sched_barrier(0);
      compute(cbuf);
      cbuf = (cbuf == 2) ? 0 : cbuf + 1;
    }

    // Epilogue. C/D: col = lane&15 (j), row = quad*4 + reg (i). Reduce d^2.
    int jgc[2]; float sqj[2];
    #pragma unroll
    for (int tj2 = 0; tj2 < 2; tj2++) {
      jgc[tj2] = imin(j0 + wj * 32 + tj2 * 16 + lr, jend - 1);
      sqj[tj2] = sq[jgc[tj2]];
    }
    float cred[2];
    cred[0] = cred[1] = diag ? 0.f : INFINITY;

    #pragma unroll
    for (int ti2 = 0; ti2 < 2; ti2++) {
      #pragma unroll
      for (int r = 0; r < 4; r++) {
        int ir = imin(i0 + wi * 32 + ti2 * 16 + quad * 4 + r, iend - 1);
        float sqi = sq[ir];
        float v = diag ? 0.f : INFINITY;
        #pragma unroll
        for (int tj2 = 0; tj2 < 2; tj2++) {
          float d2 = fmaxf(sqi + sqj[tj2] - 2.f * acc[ti2][tj2][r], 1e-12f);
          v = diag ? fmaxf(v, d2) : fminf(v, d2);
          cred[tj2] = diag ? fmaxf(cred[tj2], d2) : fminf(cred[tj2], d2);
        }
        #pragma unroll
        for (int m = 1; m < 16; m <<= 1) {
          float o = __shfl_xor(v, m);
          v = diag ? fmaxf(v, o) : fminf(v, o);
        }
        if (lr == 0) {
          unsigned int u = __float_as_uint(sqrtf(v));
          if (diag) atomicMax(ap + ir, u);
          else      atomicMin(an + ir, u);
        }
      }
    }
    if (colside) {
      #pragma unroll
      for (int tj2 = 0; tj2 < 2; tj2++) {
        float v = cred[tj2];
        float o = __shfl_xor(v, 16);
        v = diag ? fmaxf(v, o) : fminf(v, o);
        o = __shfl_xor(v, 32);
        v = diag ? fmaxf(v, o) : fminf(v, o);
        if (quad == 0) {
          unsigned int u = __float_as_uint(sqrtf(v));
          if (diag) atomicMax(ap + jgc[tj2], u);
          else      atomicMin(an + jgc[tj2], u);
        }
      }
    }
    // Protect LDS buffers before next tile's stage() overwrites them.
    __builtin_amdgcn_s_barrier();
  }

  // ---- last-block ticket: final loss reduction --------------------------
  __syncthreads();
  if (t == 0) {
    __threadfence();
    int ticket = __hip_atomic_fetch_add(done, 1, __ATOMIC_ACQ_REL,
                                        __HIP_MEMORY_SCOPE_AGENT);
    s_islast = (ticket == GRID - 1);
  }
  __syncthreads();
  if (s_islast) {
    int has = flag[0];
    float s = 0.f;
    for (int i = t; i < N; i += 256) {
      unsigned int au = __hip_atomic_load(ap + i, __ATOMIC_RELAXED,
                                          __HIP_MEMORY_SCOPE_AGENT);
      unsigned int nu = __hip_atomic_load(an + i, __ATOMIC_RELAXED,
                                          __HIP_MEMORY_SCOPE_AGENT);
      float a = __uint_as_float(au);
      float bb = has ? __uint_as_float(nu) : 0.f;
      s += fmaxf(a - bb + MARGIN, 0.f);
    }
    #pragma unroll
    for (int m = 32; m; m >>= 1) s += __shfl_xor(s, m);
    if ((t & 63) == 0) wred[t >> 6] = s;
    __syncthreads();
    if (t == 0) out[0] = (wred[0] + wred[1] + wred[2] + wred[3]) / (float)N;
  }
}

// ---------------------------------------------------------------------------
extern "C" void kernel_launch(void* const* d_in, const int* in_sizes, int n_in,
                              void* d_out, int out_size, void* d_ws,
                              size_t ws_size, hipStream_t stream) {
  const float* X = (const float*)d_in[0];
  const int* tg = (const int*)d_in[1];
  float* out = (float*)d_out;

  char* ws = (char*)d_ws;
  __bf16* Xg = (__bf16*)ws;
  size_t o = (size_t)N * K * 2;
  float* sq = (float*)(ws + o); o += (size_t)N * 4;
  unsigned int* ap = (unsigned int*)(ws + o); o += (size_t)N * 4;
  unsigned int* an = (unsigned int*)(ws + o); o += (size_t)N * 4;
  int* cursor = (int*)(ws + o); o += NC * 4;
  int* flag = (int*)(ws + o); o += 4;
  int* done = (int*)(ws + o); o += 4;
  int* Tp = (int*)(ws + o); o += 4;
  o = (o + 15) & ~(size_t)15;
  int4* tiles = (int4*)(ws + o); o += (size_t)MAXTILES * 16;

  plan_kernel<<<1, 256, 0, stream>>>(tg, cursor, flag, done, Tp, tiles);
  convert_kernel<<<N, 256, 0, stream>>>(X, tg, Xg, sq, ap, an, cursor);
  gemm_reduce_kernel<<<GRID, 256, 0, stream>>>(Xg, sq, Tp, tiles, flag, done,
                                               ap, an, out);
}